// Round 7
// baseline (491.120 us; speedup 1.0000x reference)
//
#include <hip/hip_runtime.h>

// Problem constants
#define NB 2
#define NN 2048
#define NC 768
#define NH 12
#define ND 64
#define ROWS (NB * NN)      // 4096
#define K3C (3 * NC)        // 2304
#define NHEADS (NB * NH)    // 24
#define NKB 12              // 768 / 64 K-blocks
#define ATTN_SCALE 0.125f   // 64^-0.5

typedef __attribute__((ext_vector_type(8))) short s16x8;
typedef __attribute__((ext_vector_type(4))) float f32x4;
typedef __attribute__((ext_vector_type(2))) unsigned int u32x2;

// ---------------------------------------------------------------------------
// helpers
// ---------------------------------------------------------------------------
__device__ __forceinline__ float qsc(const unsigned* u) {
    return __uint_as_float(*u) / 127.0f + 1e-8f;   // s = max|t|/127 + 1e-8
}
__device__ __forceinline__ float fq(float t, float s) {
    return fminf(fmaxf(rintf(t / s), -127.0f), 127.0f) * s;
}
__device__ __forceinline__ float qcode(float t, float s) {   // integer code as f32 (exact div)
    return fminf(fmaxf(rintf(t / s), -127.0f), 127.0f);
}
__device__ __forceinline__ short bfbits(float f) {           // exact for ints<=127 & pow2
    return (short)(__float_as_uint(f) >> 16);
}
__device__ __forceinline__ ushort bf_rne(float x) {          // round-to-nearest-even bf16
    unsigned u = __float_as_uint(x);
    return (ushort)((u + 0x7fffu + ((u >> 16) & 1u)) >> 16);
}
// async global->LDS, 16B per lane; lds base must be wave-uniform
__device__ __forceinline__ void glds16(const void* g, void* lds) {
    __builtin_amdgcn_global_load_lds((const __attribute__((address_space(1))) unsigned int*)g,
                                     (__attribute__((address_space(3))) unsigned int*)lds,
                                     16, 0, 0);
}

// ---------------------------------------------------------------------------
// max |x| reduction (weights only)
// ---------------------------------------------------------------------------
__global__ __launch_bounds__(256) void maxabs_kernel(const float* __restrict__ x,
                                                     long long n, unsigned* out) {
    float m = 0.0f;
    long long stride4 = (long long)gridDim.x * blockDim.x * 4;
    for (long long j = ((long long)blockIdx.x * blockDim.x + threadIdx.x) * 4; j < n; j += stride4) {
        float4 v = *(const float4*)(x + j);
        m = fmaxf(m, fmaxf(fmaxf(fabsf(v.x), fabsf(v.y)), fmaxf(fabsf(v.z), fabsf(v.w))));
    }
    for (int off = 32; off > 0; off >>= 1) m = fmaxf(m, __shfl_down(m, off, 64));
    __shared__ float sm[4];
    int lane = threadIdx.x & 63, w = threadIdx.x >> 6;
    if (lane == 0) sm[w] = m;
    __syncthreads();
    if (threadIdx.x == 0) {
        float mm = fmaxf(fmaxf(sm[0], sm[1]), fmaxf(sm[2], sm[3]));
        atomicMax(out, __float_as_uint(mm));
    }
}

// ---------------------------------------------------------------------------
// elementwise fake-quant
// ---------------------------------------------------------------------------
__global__ __launch_bounds__(256) void quant_kernel(const float* in, float* out,
                                                    long long n, const unsigned* umax) {
    float s = qsc(umax);
    long long stride4 = (long long)gridDim.x * blockDim.x * 4;
    for (long long j = ((long long)blockIdx.x * blockDim.x + threadIdx.x) * 4; j < n; j += stride4) {
        float4 v = *(const float4*)(in + j);
        v.x = fq(v.x, s); v.y = fq(v.y, s); v.z = fq(v.z, s); v.w = fq(v.w, s);
        *(float4*)(out + j) = v;
    }
}

// ---------------------------------------------------------------------------
// f32 -> integer codes as bf16 bits, ROW-MAJOR (for attention)
// ---------------------------------------------------------------------------
__global__ __launch_bounds__(256) void quantcodes_kernel(const float* __restrict__ in,
                                                         ushort* __restrict__ codes,
                                                         long long n,
                                                         const unsigned* __restrict__ umax) {
    float s = qsc(umax);
    long long stride8 = (long long)gridDim.x * blockDim.x * 8;
    for (long long j = ((long long)blockIdx.x * blockDim.x + threadIdx.x) * 8; j < n; j += stride8) {
        float4 a = *(const float4*)(in + j);
        float4 b = *(const float4*)(in + j + 4);
        s16x8 o;
        o[0] = bfbits(qcode(a.x, s)); o[1] = bfbits(qcode(a.y, s));
        o[2] = bfbits(qcode(a.z, s)); o[3] = bfbits(qcode(a.w, s));
        o[4] = bfbits(qcode(b.x, s)); o[5] = bfbits(qcode(b.y, s));
        o[6] = bfbits(qcode(b.z, s)); o[7] = bfbits(qcode(b.w, s));
        *(s16x8*)(codes + j) = o;
    }
}

// ---------------------------------------------------------------------------
// f32 weights [Nr][768] -> codes in GEMM-tile layout:
// tile(rb=r>>7, kb=k>>6) of 128x64, row r&127, col-group swizzled (u ^ (r&7)).
// ---------------------------------------------------------------------------
__global__ __launch_bounds__(256) void quantcodes_tiled_kernel(const float* __restrict__ in,
                                                               ushort* __restrict__ codes,
                                                               long long n,
                                                               const unsigned* __restrict__ umax) {
    float s = qsc(umax);
    long long stride8 = (long long)gridDim.x * blockDim.x * 8;
    for (long long j = ((long long)blockIdx.x * blockDim.x + threadIdx.x) * 8; j < n; j += stride8) {
        long long r = j / NC;
        int k = (int)(j % NC);
        float4 a = *(const float4*)(in + j);
        float4 b = *(const float4*)(in + j + 4);
        s16x8 o;
        o[0] = bfbits(qcode(a.x, s)); o[1] = bfbits(qcode(a.y, s));
        o[2] = bfbits(qcode(a.z, s)); o[3] = bfbits(qcode(a.w, s));
        o[4] = bfbits(qcode(b.x, s)); o[5] = bfbits(qcode(b.y, s));
        o[6] = bfbits(qcode(b.z, s)); o[7] = bfbits(qcode(b.w, s));
        int u = (k & 63) >> 3;
        size_t dst = ((size_t)(r >> 7) * NKB + (k >> 6)) * 8192
                   + (size_t)(r & 127) * 64 + (((u ^ (int)(r & 7))) << 3);
        *(s16x8*)(codes + dst) = o;
    }
}

// ---------------------------------------------------------------------------
// f32 [R][768] -> 3-term bf16 split in GEMM-tile layout:
// tile(rb=r>>6, kb=k>>6): [3 planes][64 rows][64 cols swizzled] = 12288 ushorts.
// ---------------------------------------------------------------------------
__global__ __launch_bounds__(256) void split3_tiled_kernel(const float* __restrict__ in,
                                                           ushort* __restrict__ xs,
                                                           long long n) {
    long long stride8 = (long long)gridDim.x * blockDim.x * 8;
    for (long long j = ((long long)blockIdx.x * blockDim.x + threadIdx.x) * 8; j < n; j += stride8) {
        long long r = j / NC;
        int k = (int)(j % NC);
        s16x8 h, m, l;
#pragma unroll
        for (int i = 0; i < 8; i += 4) {
            float4 v = *(const float4*)(in + j + i);
            float vv[4] = {v.x, v.y, v.z, v.w};
#pragma unroll
            for (int t = 0; t < 4; ++t) {
                ushort hb = bf_rne(vv[t]);
                float hf = __uint_as_float(((unsigned)hb) << 16);
                float r1 = vv[t] - hf;
                ushort mb = bf_rne(r1);
                float mf = __uint_as_float(((unsigned)mb) << 16);
                h[i + t] = (short)hb;
                m[i + t] = (short)mb;
                l[i + t] = (short)bf_rne(r1 - mf);
            }
        }
        int u = (k & 63) >> 3;
        size_t base = ((size_t)(r >> 6) * NKB + (k >> 6)) * 12288
                    + (size_t)(r & 63) * 64 + (((u ^ (int)(r & 7))) << 3);
        *(s16x8*)(xs + base) = h;
        *(s16x8*)(xs + base + 4096) = m;
        *(s16x8*)(xs + base + 8192) = l;
    }
}

// ---------------------------------------------------------------------------
// MFMA GEMM with global_load_lds staging from pre-swizzled tiled operands.
// BM=64, BN=128, BK=64, 4 waves (1x4). C = sB*sum((hi+mid+lo)*n) + bias.
// Fused maxabs of C into uC.
// ---------------------------------------------------------------------------
__global__ __launch_bounds__(256) void gemm_glds_kernel(const ushort* __restrict__ As,
                                                        const ushort* __restrict__ Bc,
                                                        const float* __restrict__ bias,
                                                        float* __restrict__ Cm, int Nn,
                                                        const unsigned* __restrict__ uB,
                                                        unsigned* __restrict__ uC) {
    __shared__ ushort aT[3 * 64 * 64];   // 24 KB
    __shared__ ushort bT[128 * 64];      // 16 KB
    __shared__ float redmx[4];
    const float sB = qsc(uB);
    const int tid = threadIdx.x, l = tid & 63, w = tid >> 6;
    // XCD-chunked bijective swizzle (nwg % 8 == 0 for both GEMMs)
    const int nbx = Nn >> 7;
    const int nwg = nbx * (ROWS / 64);
    int bid = blockIdx.y * nbx + blockIdx.x;
    int cpx = nwg >> 3;
    int swz = (bid & 7) * cpx + (bid >> 3);
    int bx = swz % nbx, by = swz / nbx;

    f32x4 acc[4][2];
#pragma unroll
    for (int m = 0; m < 4; ++m)
#pragma unroll
        for (int n = 0; n < 2; ++n) acc[m][n] = (f32x4){0.f, 0.f, 0.f, 0.f};

    const char* tA = (const char*)As + (size_t)by * NKB * 24576;
    const char* tB = (const char*)Bc + (size_t)bx * NKB * 16384;
    const int lq = l & 15, lg = l >> 4;

    for (int kb = 0; kb < NKB; ++kb) {
#pragma unroll
        for (int i = 0; i < 6; ++i)
            glds16(tA + (size_t)i * 4096 + w * 1024 + l * 16,
                   (char*)aT + i * 4096 + w * 1024);
#pragma unroll
        for (int i = 0; i < 4; ++i)
            glds16(tB + (size_t)i * 4096 + w * 1024 + l * 16,
                   (char*)bT + i * 4096 + w * 1024);
        tA += 24576; tB += 16384;
        __syncthreads();
#pragma unroll
        for (int ks = 0; ks < 2; ++ks) {
            s16x8 bf[2];
#pragma unroll
            for (int nf = 0; nf < 2; ++nf) {
                int br = w * 32 + nf * 16 + lq;
                bf[nf] = *(s16x8*)(bT + br * 64 + ((((ks << 2) + lg) ^ (br & 7)) << 3));
            }
#pragma unroll
            for (int m = 0; m < 4; ++m) {
                int ar = m * 16 + lq;
                int ao = ar * 64 + ((((ks << 2) + lg) ^ (ar & 7)) << 3);
                s16x8 af = *(s16x8*)(aT + ao);
                s16x8 mf_ = *(s16x8*)(aT + 4096 + ao);
                s16x8 ef = *(s16x8*)(aT + 8192 + ao);
#pragma unroll
                for (int nf = 0; nf < 2; ++nf) {
                    acc[m][nf] = __builtin_amdgcn_mfma_f32_16x16x32_bf16(af, bf[nf], acc[m][nf], 0, 0, 0);
                    acc[m][nf] = __builtin_amdgcn_mfma_f32_16x16x32_bf16(mf_, bf[nf], acc[m][nf], 0, 0, 0);
                    acc[m][nf] = __builtin_amdgcn_mfma_f32_16x16x32_bf16(ef, bf[nf], acc[m][nf], 0, 0, 0);
                }
            }
        }
        __syncthreads();
    }
    // epilogue: C = sB*acc + bias, fused max|C|
    float mx = 0.0f;
#pragma unroll
    for (int nf = 0; nf < 2; ++nf) {
        int col = bx * 128 + w * 32 + nf * 16 + lq;
        float bv = bias[col];
#pragma unroll
        for (int m = 0; m < 4; ++m) {
            int grow = by * 64 + m * 16 + (lg << 2);
#pragma unroll
            for (int r = 0; r < 4; ++r) {
                float v = fmaf(sB, acc[m][nf][r], bv);
                Cm[(size_t)(grow + r) * Nn + col] = v;
                mx = fmaxf(mx, fabsf(v));
            }
        }
    }
    for (int msk = 1; msk < 64; msk <<= 1) mx = fmaxf(mx, __shfl_xor(mx, msk, 64));
    if (l == 0) redmx[w] = mx;
    __syncthreads();
    if (tid == 0)
        atomicMax(uC, __float_as_uint(fmaxf(fmaxf(redmx[0], redmx[1]), fmaxf(redmx[2], redmx[3]))));
}

// ---------------------------------------------------------------------------
// stage a 64(seq) x 64(d) V tile TRANSPOSED into swizzled LDS: vt[d][j].
// ---------------------------------------------------------------------------
__device__ __forceinline__ void stage_vT_tile(const ushort* __restrict__ src,
                                              ushort* lds, int tid) {
    int j = tid >> 2, d0 = (tid & 3) << 4;
    const ushort* p = src + (size_t)j * K3C + d0;
    s16x8 a = *(const s16x8*)(p);
    s16x8 b = *(const s16x8*)(p + 8);
    int jo = j >> 3, jl = j & 7;
#pragma unroll
    for (int t = 0; t < 8; ++t) {
        int d = d0 + t;
        lds[d * 64 + ((jo ^ (d & 7)) << 3) + jl] = (ushort)a[t];
    }
#pragma unroll
    for (int t = 0; t < 8; ++t) {
        int d = d0 + 8 + t;
        lds[d * 64 + ((jo ^ (d & 7)) << 3) + jl] = (ushort)b[t];
    }
}

// ---------------------------------------------------------------------------
// pass A: global max |dot_int|. 1 wave per 16 q-rows; K read direct (L2-hot),
// no LDS, no barriers.
// ---------------------------------------------------------------------------
__global__ __launch_bounds__(64) void attn_maxdot_kernel(const ushort* __restrict__ codes,
                                                         unsigned* __restrict__ umaxdot) {
    int bh = blockIdx.y, b = bh / NH, h = bh % NH;
    int i0 = blockIdx.x << 4;
    int l = threadIdx.x, qr = l & 15, g = l >> 4;

    const ushort* qp = codes + (size_t)(b * NN + i0 + qr) * K3C + h * ND + (g << 3);
    s16x8 qf0 = *(const s16x8*)(qp);
    s16x8 qf1 = *(const s16x8*)(qp + 32);

    const ushort* kl = codes + ((size_t)b * NN + qr) * K3C + NC + h * ND + (g << 3);
    float md = 0.0f;
    for (int st = 0; st < NN / 64; ++st) {
        const ushort* kt0 = kl + (size_t)st * 64 * K3C;
#pragma unroll
        for (int jt = 0; jt < 4; ++jt) {
            s16x8 kf0 = *(const s16x8*)(kt0 + (size_t)jt * 16 * K3C);
            s16x8 kf1 = *(const s16x8*)(kt0 + (size_t)jt * 16 * K3C + 32);
            f32x4 acc = {0.f, 0.f, 0.f, 0.f};
            acc = __builtin_amdgcn_mfma_f32_16x16x32_bf16(kf0, qf0, acc, 0, 0, 0);
            acc = __builtin_amdgcn_mfma_f32_16x16x32_bf16(kf1, qf1, acc, 0, 0, 0);
#pragma unroll
            for (int r = 0; r < 4; ++r) md = fmaxf(md, fabsf(acc[r]));
        }
    }
    for (int m = 1; m < 64; m <<= 1) md = fmaxf(md, __shfl_xor(md, m, 64));
    if (l == 0) atomicMax(umaxdot, __float_as_uint(md));
}

// ---------------------------------------------------------------------------
// fused log-int-softmax + PV. K read direct from L2 (no staging, no barriers
// in sweep 1); V staged transposed in LDS (sweep 2 only).
// ---------------------------------------------------------------------------
__global__ __launch_bounds__(256) void attn_fused_kernel(const ushort* __restrict__ codes,
                                                         const unsigned* __restrict__ uq,
                                                         const unsigned* __restrict__ umaxdot,
                                                         float* __restrict__ O) {
    __shared__ ushort vt[64 * 64];
    __shared__ ushort ps[4][16 * 64];
    int bh = blockIdx.y, b = bh / NH, h = bh % NH;
    int i0 = blockIdx.x * 64;
    int tid = threadIdx.x, l = tid & 63, w = tid >> 6;
    int qr = l & 15, g = l >> 4;
    float s = qsc(uq);
    float cf = s * s * ATTN_SCALE;
    float sa = __uint_as_float(*umaxdot) * cf / 127.0f + 1e-8f;  // s_attn
    float rr = cf / sa;                                          // dot -> attn-code
    float kk = sa * 1.44269504088896340736f;                     // s_attn * log2(e)

    const ushort* qp = codes + (size_t)(b * NN + i0 + w * 16 + qr) * K3C + h * ND + (g << 3);
    s16x8 qf0 = *(const s16x8*)(qp);
    s16x8 qf1 = *(const s16x8*)(qp + 32);

    const ushort* kl = codes + ((size_t)b * NN + qr) * K3C + NC + h * ND + (g << 3);
    const ushort* vbase = codes + (size_t)(b * NN) * K3C + 2 * NC + h * ND;

    // ---- sweep 1: U = sum_j exp(aq), no barriers ----
    float U = 0.0f;
    for (int st = 0; st < NN / 64; ++st) {
        const ushort* kt0 = kl + (size_t)st * 64 * K3C;
#pragma unroll
        for (int jt = 0; jt < 4; ++jt) {
            s16x8 kf0 = *(const s16x8*)(kt0 + (size_t)jt * 16 * K3C);
            s16x8 kf1 = *(const s16x8*)(kt0 + (size_t)jt * 16 * K3C + 32);
            f32x4 acc = {0.f, 0.f, 0.f, 0.f};
            acc = __builtin_amdgcn_mfma_f32_16x16x32_bf16(kf0, qf0, acc, 0, 0, 0);
            acc = __builtin_amdgcn_mfma_f32_16x16x32_bf16(kf1, qf1, acc, 0, 0, 0);
#pragma unroll
            for (int r = 0; r < 4; ++r) {
                float m = rintf(acc[r] * rr);          // |dot*rr| < 127.0001 -> no clamp
                U += exp2f(kk * m);
            }
        }
    }
    U += __shfl_xor(U, 16, 64);
    U += __shfl_xor(U, 32, 64);
    float lu = log2f(U);

    // ---- sweep 2: scores -> packed pbits -> PV ----
    f32x4 oacc[4];
#pragma unroll
    for (int dt = 0; dt < 4; ++dt) oacc[dt] = (f32x4){0.f, 0.f, 0.f, 0.f};
    ushort* myps = (ushort*)ps[w];
    for (int st = 0; st < NN / 64; ++st) {
        __syncthreads();
        stage_vT_tile(vbase + (size_t)st * 64 * K3C, vt, tid);
        __syncthreads();
        const ushort* kt0 = kl + (size_t)st * 64 * K3C;
#pragma unroll
        for (int jt = 0; jt < 4; ++jt) {
            s16x8 kf0 = *(const s16x8*)(kt0 + (size_t)jt * 16 * K3C);
            s16x8 kf1 = *(const s16x8*)(kt0 + (size_t)jt * 16 * K3C + 32);
            f32x4 acc = {0.f, 0.f, 0.f, 0.f};
            acc = __builtin_amdgcn_mfma_f32_16x16x32_bf16(kf0, qf0, acc, 0, 0, 0);
            acc = __builtin_amdgcn_mfma_f32_16x16x32_bf16(kf1, qf1, acc, 0, 0, 0);
            int lg[4];
#pragma unroll
            for (int r = 0; r < 4; ++r) {
                float m = rintf(acc[r] * rr);
                float tt = lu - kk * m;
                lg[r] = (int)fminf(fmaxf(rintf(tt), 0.0f), 15.0f);
            }
            unsigned w0 = (unsigned)(((127 - lg[0]) << 7) | ((127 - lg[1]) << 23));
            unsigned w1 = (unsigned)(((127 - lg[2]) << 7) | ((127 - lg[3]) << 23));
            int off = qr * 64 + (((jt << 4) + ((g >> 1) << 3)) ^ ((qr & 7) << 3)) + ((g & 1) << 2);
            *(u32x2*)(myps + off) = (u32x2){w0, w1};
        }
        // PV: O[16 x 64] += P[16 x 64] * V[64 x 64]
#pragma unroll
        for (int kc = 0; kc < 2; ++kc) {
            int poff = qr * 64 + (((kc << 5) + (g << 3)) ^ ((qr & 7) << 3));
            s16x8 pf = *(s16x8*)(myps + poff);
#pragma unroll
            for (int dt = 0; dt < 4; ++dt) {
                int drow = (dt << 4) + qr;
                s16x8 vf = *(s16x8*)(vt + drow * 64 + ((((kc << 2) + g) ^ (drow & 7)) << 3));
                oacc[dt] = __builtin_amdgcn_mfma_f32_16x16x32_bf16(pf, vf, oacc[dt], 0, 0, 0);
            }
        }
    }
    // write O (scale codes back by s_qkv)
#pragma unroll
    for (int dt = 0; dt < 4; ++dt)
#pragma unroll
        for (int r = 0; r < 4; ++r) {
            int orow = i0 + w * 16 + (g << 2) + r;
            O[(size_t)(b * NN + orow) * NC + h * ND + (dt << 4) + qr] = s * oacc[dt][r];
        }
}

// ---------------------------------------------------------------------------
// launch
// ---------------------------------------------------------------------------
extern "C" void kernel_launch(void* const* d_in, const int* in_sizes, int n_in,
                              void* d_out, int out_size, void* d_ws, size_t ws_size,
                              hipStream_t stream) {
    const float* x      = (const float*)d_in[0];
    const float* w_qkv  = (const float*)d_in[1];
    const float* b_qkv  = (const float*)d_in[2];
    const float* w_out  = (const float*)d_in[3];
    const float* b_out  = (const float*)d_in[4];
    float* out = (float*)d_out;

    // ---- workspace layout (56.6 MB envelope, lifetime-overlapped) ----
    char* ws = (char*)d_ws;
    unsigned* u = (unsigned*)ws;                  // 0:wqkv 1:wout 2:qkv 3:maxdot 4:out
    const size_t qkvB = (size_t)ROWS * K3C * 4;            // 37.75 MB
    float*  qkv     = (float*)(ws + 256);                  // f32 qkv (gemm1..quantcodes)
    float*  out_tmp = (float*)(ws + 256);                  // gemm2 out (after qkv dead)
    ushort* woc     = (ushort*)(ws + 256 + 16 * 1024 * 1024);  // w_out codes tiled, 1.18 MB
    char*   codesRg = ws + 256 + qkvB;                     // 18.87 MB region
    ushort* codes   = (ushort*)codesRg;                    // qkv codes (row-major, attention)
    ushort* xsplit  = (ushort*)codesRg;                    // 3-term split tiled (x / O)
    ushort* wqc     = (ushort*)d_out;                      // w_qkv codes tiled in d_out (3.54 MB)

    hipMemsetAsync(u, 0, 64, stream);

    // weight maxima + tiled codes
    maxabs_kernel<<<512, 256, 0, stream>>>(w_qkv, (long long)K3C * NC, u + 0);
    maxabs_kernel<<<512, 256, 0, stream>>>(w_out, (long long)NC * NC, u + 1);
    quantcodes_tiled_kernel<<<512, 256, 0, stream>>>(w_qkv, wqc, (long long)K3C * NC, u + 0);

    // x -> tiled 3-term split, then GEMM1 (fused maxabs -> u+2)
    split3_tiled_kernel<<<1024, 256, 0, stream>>>(x, xsplit, (long long)ROWS * NC);
    gemm_glds_kernel<<<dim3(K3C / 128, ROWS / 64), 256, 0, stream>>>(xsplit, wqc, b_qkv,
                                                                     qkv, K3C, u + 0, u + 2);
    // qact_qkv -> row-major codes (clobbers xsplit, dead)
    quantcodes_kernel<<<2048, 256, 0, stream>>>(qkv, codes, (long long)ROWS * K3C, u + 2);
    // w_out tiled codes into dead qkv-f32 region (after quantcodes above)
    quantcodes_tiled_kernel<<<256, 256, 0, stream>>>(w_out, woc, (long long)NC * NC, u + 1);

    // attention (O f32 -> d_out; clobbers wqc, dead)
    attn_maxdot_kernel<<<dim3(NN / 16, NHEADS), 64, 0, stream>>>(codes, u + 3);
    attn_fused_kernel<<<dim3(NN / 64, NHEADS), 256, 0, stream>>>(codes, u + 2, u + 3, out);

    // O -> tiled split (clobbers codes, dead), then GEMM2 (fused maxabs -> u+4)
    split3_tiled_kernel<<<1024, 256, 0, stream>>>(out, xsplit, (long long)ROWS * NC);
    gemm_glds_kernel<<<dim3(NC / 128, ROWS / 64), 256, 0, stream>>>(xsplit, woc, b_out,
                                                                    out_tmp, NC, u + 1, u + 4);
    // qact_out -> d_out
    quant_kernel<<<1024, 256, 0, stream>>>(out_tmp, out, (long long)ROWS * NC, u + 4);
}

// Round 9
// 361.950 us; speedup vs baseline: 1.3569x; 1.3569x over previous
//
#include <hip/hip_runtime.h>

// Problem constants
#define NB 2
#define NN 2048
#define NC 768
#define NH 12
#define ND 64
#define ROWS (NB * NN)      // 4096
#define K3C (3 * NC)        // 2304
#define NHEADS (NB * NH)    // 24
#define NT 32               // NN/64 K-tiles
#define ATTN_SCALE 0.125f   // 64^-0.5

typedef __attribute__((ext_vector_type(8))) short s16x8;
typedef __attribute__((ext_vector_type(4))) float f32x4;
typedef __attribute__((ext_vector_type(2))) unsigned int u32x2;

// ---------------------------------------------------------------------------
// helpers
// ---------------------------------------------------------------------------
__device__ __forceinline__ float qsc(const unsigned* u) {
    return __uint_as_float(*u) / 127.0f + 1e-8f;   // s = max|t|/127 + 1e-8
}
__device__ __forceinline__ float fq(float t, float s) {
    return fminf(fmaxf(rintf(t / s), -127.0f), 127.0f) * s;
}
__device__ __forceinline__ float qcode(float t, float s) {   // integer code as f32 (exact div)
    return fminf(fmaxf(rintf(t / s), -127.0f), 127.0f);
}
__device__ __forceinline__ short bfbits(float f) {           // exact for ints<=127 & pow2
    return (short)(__float_as_uint(f) >> 16);
}
__device__ __forceinline__ ushort bf_rne(float x) {          // round-to-nearest-even bf16
    unsigned u = __float_as_uint(x);
    return (ushort)((u + 0x7fffu + ((u >> 16) & 1u)) >> 16);
}

// ---------------------------------------------------------------------------
// max |x| reduction (weights only)
// ---------------------------------------------------------------------------
__global__ __launch_bounds__(256) void maxabs_kernel(const float* __restrict__ x,
                                                     long long n, unsigned* out) {
    float m = 0.0f;
    long long stride4 = (long long)gridDim.x * blockDim.x * 4;
    for (long long j = ((long long)blockIdx.x * blockDim.x + threadIdx.x) * 4; j < n; j += stride4) {
        float4 v = *(const float4*)(x + j);
        m = fmaxf(m, fmaxf(fmaxf(fabsf(v.x), fabsf(v.y)), fmaxf(fabsf(v.z), fabsf(v.w))));
    }
    for (int off = 32; off > 0; off >>= 1) m = fmaxf(m, __shfl_down(m, off, 64));
    __shared__ float sm[4];
    int lane = threadIdx.x & 63, w = threadIdx.x >> 6;
    if (lane == 0) sm[w] = m;
    __syncthreads();
    if (threadIdx.x == 0) {
        float mm = fmaxf(fmaxf(sm[0], sm[1]), fmaxf(sm[2], sm[3]));
        atomicMax(out, __float_as_uint(mm));
    }
}

// ---------------------------------------------------------------------------
// elementwise fake-quant
// ---------------------------------------------------------------------------
__global__ __launch_bounds__(256) void quant_kernel(const float* in, float* out,
                                                    long long n, const unsigned* umax) {
    float s = qsc(umax);
    long long stride4 = (long long)gridDim.x * blockDim.x * 4;
    for (long long j = ((long long)blockIdx.x * blockDim.x + threadIdx.x) * 4; j < n; j += stride4) {
        float4 v = *(const float4*)(in + j);
        v.x = fq(v.x, s); v.y = fq(v.y, s); v.z = fq(v.z, s); v.w = fq(v.w, s);
        *(float4*)(out + j) = v;
    }
}

// ---------------------------------------------------------------------------
// f32 -> integer codes stored as bf16 bits (exact division, bit-identical
// to the reference's quant decisions). codes are ints in [-127,127].
// ---------------------------------------------------------------------------
__global__ __launch_bounds__(256) void quantcodes_kernel(const float* __restrict__ in,
                                                         ushort* __restrict__ codes,
                                                         long long n,
                                                         const unsigned* __restrict__ umax) {
    float s = qsc(umax);
    long long stride8 = (long long)gridDim.x * blockDim.x * 8;
    for (long long j = ((long long)blockIdx.x * blockDim.x + threadIdx.x) * 8; j < n; j += stride8) {
        float4 a = *(const float4*)(in + j);
        float4 b = *(const float4*)(in + j + 4);
        s16x8 o;
        o[0] = bfbits(qcode(a.x, s)); o[1] = bfbits(qcode(a.y, s));
        o[2] = bfbits(qcode(a.z, s)); o[3] = bfbits(qcode(a.w, s));
        o[4] = bfbits(qcode(b.x, s)); o[5] = bfbits(qcode(b.y, s));
        o[6] = bfbits(qcode(b.z, s)); o[7] = bfbits(qcode(b.w, s));
        *(s16x8*)(codes + j) = o;
    }
}

// ---------------------------------------------------------------------------
// f32 [R][768] -> 3-term bf16 split stored [R][2304]: hi | mid | lo planes.
// ---------------------------------------------------------------------------
__global__ __launch_bounds__(256) void split3_kernel(const float* __restrict__ in,
                                                     ushort* __restrict__ xs,
                                                     long long n) {
    long long stride8 = (long long)gridDim.x * blockDim.x * 8;
    for (long long j = ((long long)blockIdx.x * blockDim.x + threadIdx.x) * 8; j < n; j += stride8) {
        long long row = j / NC, col = j % NC;
        s16x8 h, m, l;
#pragma unroll
        for (int i = 0; i < 8; i += 4) {
            float4 v = *(const float4*)(in + j + i);
            float vv[4] = {v.x, v.y, v.z, v.w};
#pragma unroll
            for (int t = 0; t < 4; ++t) {
                ushort hb = bf_rne(vv[t]);
                float hf = __uint_as_float(((unsigned)hb) << 16);
                float r1 = vv[t] - hf;
                ushort mb = bf_rne(r1);
                float mf = __uint_as_float(((unsigned)mb) << 16);
                h[i + t] = (short)hb;
                m[i + t] = (short)mb;
                l[i + t] = (short)bf_rne(r1 - mf);
            }
        }
        ushort* dst = xs + row * (3 * NC) + col;
        *(s16x8*)(dst) = h;
        *(s16x8*)(dst + NC) = m;
        *(s16x8*)(dst + 2 * NC) = l;
    }
}

// ---------------------------------------------------------------------------
// MFMA GEMM: C[i,j] = sB * sum_k (hi+mid+lo)_ik * n_jk + bias[j]
// 128x128 tile, 4 waves (2x2), BK=64, XCD-chunked block swizzle.
// Fused maxabs of C into uC.
// ---------------------------------------------------------------------------
__global__ __launch_bounds__(256) void gemm3_mfma_kernel(const ushort* __restrict__ As,
                                                         const ushort* __restrict__ Bc,
                                                         const float* __restrict__ bias,
                                                         float* __restrict__ Cm, int Nn,
                                                         const unsigned* __restrict__ uB,
                                                         unsigned* __restrict__ uC) {
    __shared__ ushort ah[128 * 64], am[128 * 64], al[128 * 64], bs[128 * 64];
    __shared__ float redmx[4];
    const float sB = qsc(uB);
    const int tid = threadIdx.x, l = tid & 63, w = tid >> 6;
    // XCD bijective chunked swizzle (nwg % 8 == 0 for both GEMMs: 576, 192)
    const int nbx = Nn >> 7;
    const int nwg = nbx * (ROWS >> 7);
    int bid = blockIdx.y * nbx + blockIdx.x;
    int swz = (bid & 7) * (nwg >> 3) + (bid >> 3);
    const int row0 = (swz / nbx) * 128, col0 = (swz % nbx) * 128;
    const int wr = w >> 1, wc = w & 1;
    f32x4 acc[4][4];
#pragma unroll
    for (int m = 0; m < 4; ++m)
#pragma unroll
        for (int n = 0; n < 4; ++n) acc[m][n] = (f32x4){0.f, 0.f, 0.f, 0.f};

    const int sr = tid >> 1, sh = (tid & 1) << 5;   // stage: row 0..127, k-off 0/32
    const int su = sh >> 3, s7 = sr & 7;

    for (int k0 = 0; k0 < NC; k0 += 64) {
        __syncthreads();
        {   // A hi/mid/lo tiles
            const ushort* ph = As + (size_t)(row0 + sr) * (3 * NC) + k0 + sh;
            ushort* dsts[3] = {ah + sr * 64, am + sr * 64, al + sr * 64};
#pragma unroll
            for (int pl = 0; pl < 3; ++pl) {
                const ushort* p = ph + pl * NC;
                s16x8 t0 = *(const s16x8*)(p),      t1 = *(const s16x8*)(p + 8);
                s16x8 t2 = *(const s16x8*)(p + 16), t3 = *(const s16x8*)(p + 24);
                ushort* d = dsts[pl];
                *(s16x8*)(d + (((su | 0) ^ s7) << 3)) = t0;
                *(s16x8*)(d + (((su | 1) ^ s7) << 3)) = t1;
                *(s16x8*)(d + (((su | 2) ^ s7) << 3)) = t2;
                *(s16x8*)(d + (((su | 3) ^ s7) << 3)) = t3;
            }
            // B tile
            const ushort* pb = Bc + (size_t)(col0 + sr) * NC + k0 + sh;
            s16x8 b0 = *(const s16x8*)(pb),      b1 = *(const s16x8*)(pb + 8);
            s16x8 b2 = *(const s16x8*)(pb + 16), b3 = *(const s16x8*)(pb + 24);
            ushort* brow = bs + sr * 64;
            *(s16x8*)(brow + (((su | 0) ^ s7) << 3)) = b0;
            *(s16x8*)(brow + (((su | 1) ^ s7) << 3)) = b1;
            *(s16x8*)(brow + (((su | 2) ^ s7) << 3)) = b2;
            *(s16x8*)(brow + (((su | 3) ^ s7) << 3)) = b3;
        }
        __syncthreads();
#pragma unroll
        for (int ks = 0; ks < 2; ++ks) {
            s16x8 bf[4];
#pragma unroll
            for (int n = 0; n < 4; ++n) {
                int br = wc * 64 + n * 16 + (l & 15);
                bf[n] = *(s16x8*)(bs + br * 64 + ((((ks << 2) + (l >> 4)) ^ (br & 7)) << 3));
            }
#pragma unroll
            for (int m = 0; m < 4; ++m) {
                int ar = wr * 64 + m * 16 + (l & 15);
                int ao = ar * 64 + ((((ks << 2) + (l >> 4)) ^ (ar & 7)) << 3);
                s16x8 af = *(s16x8*)(ah + ao);
                s16x8 mf_ = *(s16x8*)(am + ao);
                s16x8 ef = *(s16x8*)(al + ao);
#pragma unroll
                for (int n = 0; n < 4; ++n) {
                    acc[m][n] = __builtin_amdgcn_mfma_f32_16x16x32_bf16(af, bf[n], acc[m][n], 0, 0, 0);
                    acc[m][n] = __builtin_amdgcn_mfma_f32_16x16x32_bf16(mf_, bf[n], acc[m][n], 0, 0, 0);
                    acc[m][n] = __builtin_amdgcn_mfma_f32_16x16x32_bf16(ef, bf[n], acc[m][n], 0, 0, 0);
                }
            }
        }
    }
    // epilogue: C = sB*acc + bias, fused max|C|
    float mx = 0.0f;
#pragma unroll
    for (int n = 0; n < 4; ++n) {
        int col = col0 + wc * 64 + n * 16 + (l & 15);
        float bv = bias[col];
#pragma unroll
        for (int m = 0; m < 4; ++m) {
            int grow = row0 + wr * 64 + m * 16 + ((l >> 4) << 2);
#pragma unroll
            for (int r = 0; r < 4; ++r) {
                float v = fmaf(sB, acc[m][n][r], bv);
                Cm[(size_t)(grow + r) * Nn + col] = v;
                mx = fmaxf(mx, fabsf(v));
            }
        }
    }
    for (int msk = 1; msk < 64; msk <<= 1) mx = fmaxf(mx, __shfl_xor(mx, msk, 64));
    if (l == 0) redmx[w] = mx;
    __syncthreads();
    if (tid == 0)
        atomicMax(uC, __float_as_uint(fmaxf(fmaxf(redmx[0], redmx[1]), fmaxf(redmx[2], redmx[3]))));
}

// ---------------------------------------------------------------------------
// stage a 64(seq) x 64(d) tile of codes into XOR-swizzled LDS (pure copy).
// ---------------------------------------------------------------------------
__device__ __forceinline__ void stage_k_tile(const ushort* __restrict__ src,
                                             ushort* lds, int tid) {
    int row = tid >> 2, u0 = (tid & 3) << 1, r7 = row & 7;
    const ushort* p = src + (size_t)row * K3C + (u0 << 3);
    s16x8 t0 = *(const s16x8*)(p);
    s16x8 t1 = *(const s16x8*)(p + 8);
    *(s16x8*)(lds + row * 64 + ((u0 ^ r7) << 3)) = t0;
    *(s16x8*)(lds + row * 64 + (((u0 | 1) ^ r7) << 3)) = t1;
}

// stage a 64(seq) x 64(d) V tile TRANSPOSED into swizzled LDS: vt[d][j].
// Octet XOR includes (d>>3) so the 4 concurrent d-groups hit disjoint octets
// (write conflict fix); reads use the same formula.
__device__ __forceinline__ void stage_vT_tile(const ushort* __restrict__ src,
                                              ushort* lds, int tid) {
    int j = tid >> 2, d0 = (tid & 3) << 4;
    const ushort* p = src + (size_t)j * K3C + d0;
    s16x8 a = *(const s16x8*)(p);
    s16x8 b = *(const s16x8*)(p + 8);
    int jo = j >> 3, jl = j & 7;
#pragma unroll
    for (int t = 0; t < 8; ++t) {
        int d = d0 + t;
        lds[d * 64 + (((jo ^ (d & 7)) ^ ((d >> 3) & 7)) << 3) + jl] = (ushort)a[t];
    }
#pragma unroll
    for (int t = 0; t < 8; ++t) {
        int d = d0 + 8 + t;
        lds[d * 64 + (((jo ^ (d & 7)) ^ ((d >> 3) & 7)) << 3) + jl] = (ushort)b[t];
    }
}

// ---------------------------------------------------------------------------
// pass A: global max |dot_int|; double-buffered K staging, 1 barrier/tile.
// ---------------------------------------------------------------------------
__global__ __launch_bounds__(256) void attn_maxdot_kernel(const ushort* __restrict__ codes,
                                                          unsigned* __restrict__ umaxdot) {
    __shared__ ushort kt[2][64 * 64];
    __shared__ float red[4];
    int bh = blockIdx.y, b = bh / NH, h = bh % NH;
    int i0 = blockIdx.x * 64;
    int tid = threadIdx.x, l = tid & 63, w = tid >> 6;
    int qr = l & 15, g = l >> 4;

    const ushort* qp = codes + (size_t)(b * NN + i0 + w * 16 + qr) * K3C + h * ND + (g << 3);
    s16x8 qf0 = *(const s16x8*)(qp);
    s16x8 qf1 = *(const s16x8*)(qp + 32);

    const ushort* kbase = codes + (size_t)(b * NN) * K3C + NC + h * ND;
    stage_k_tile(kbase, kt[0], tid);
    float md = 0.0f;
    for (int st = 0; st < NT; ++st) {
        __syncthreads();
        if (st + 1 < NT) stage_k_tile(kbase + (size_t)(st + 1) * 64 * K3C, kt[(st + 1) & 1], tid);
        const ushort* ktc = kt[st & 1];
#pragma unroll
        for (int jt = 0; jt < 4; ++jt) {
            int row = (jt << 4) + qr;
            f32x4 acc = {0.f, 0.f, 0.f, 0.f};
            s16x8 kf0 = *(s16x8*)(ktc + row * 64 + (((g    ) ^ (row & 7)) << 3));
            s16x8 kf1 = *(s16x8*)(ktc + row * 64 + (((g + 4) ^ (row & 7)) << 3));
            acc = __builtin_amdgcn_mfma_f32_16x16x32_bf16(kf0, qf0, acc, 0, 0, 0);
            acc = __builtin_amdgcn_mfma_f32_16x16x32_bf16(kf1, qf1, acc, 0, 0, 0);
#pragma unroll
            for (int r = 0; r < 4; ++r) md = fmaxf(md, fabsf(acc[r]));
        }
    }
    for (int m = 1; m < 64; m <<= 1) md = fmaxf(md, __shfl_xor(md, m, 64));
    if (l == 0) red[w] = md;
    __syncthreads();
    if (tid == 0)
        atomicMax(umaxdot, __float_as_uint(fmaxf(fmaxf(red[0], red[1]), fmaxf(red[2], red[3]))));
}

// ---------------------------------------------------------------------------
// fused log-int-softmax + PV; double-buffered kt/vt, 1 barrier/tile.
// ---------------------------------------------------------------------------
__global__ __launch_bounds__(256) void attn_fused_kernel(const ushort* __restrict__ codes,
                                                         const unsigned* __restrict__ uq,
                                                         const unsigned* __restrict__ umaxdot,
                                                         float* __restrict__ O) {
    __shared__ ushort kt[2][64 * 64];
    __shared__ ushort vt[2][64 * 64];
    __shared__ ushort ps[4][16 * 64];
    int bh = blockIdx.y, b = bh / NH, h = bh % NH;
    int i0 = blockIdx.x * 64;
    int tid = threadIdx.x, l = tid & 63, w = tid >> 6;
    int qr = l & 15, g = l >> 4;
    float s = qsc(uq);
    float cf = s * s * ATTN_SCALE;
    float sa = __uint_as_float(*umaxdot) * cf / 127.0f + 1e-8f;  // s_attn
    float rr = cf / sa;                                          // dot -> attn-code
    float kk = sa * 1.44269504088896340736f;                     // s_attn * log2(e)

    const ushort* qp = codes + (size_t)(b * NN + i0 + w * 16 + qr) * K3C + h * ND + (g << 3);
    s16x8 qf0 = *(const s16x8*)(qp);
    s16x8 qf1 = *(const s16x8*)(qp + 32);

    const ushort* kbase = codes + (size_t)(b * NN) * K3C + NC + h * ND;
    const ushort* vbase = codes + (size_t)(b * NN) * K3C + 2 * NC + h * ND;

    // ---- sweep 1: U = sum_j exp(aq) for q-row qr ----
    stage_k_tile(kbase, kt[0], tid);
    float U = 0.0f;
    for (int st = 0; st < NT; ++st) {
        __syncthreads();
        if (st + 1 < NT) stage_k_tile(kbase + (size_t)(st + 1) * 64 * K3C, kt[(st + 1) & 1], tid);
        const ushort* ktc = kt[st & 1];
#pragma unroll
        for (int jt = 0; jt < 4; ++jt) {
            int row = (jt << 4) + qr;
            f32x4 acc = {0.f, 0.f, 0.f, 0.f};
            s16x8 kf0 = *(s16x8*)(ktc + row * 64 + (((g    ) ^ (row & 7)) << 3));
            s16x8 kf1 = *(s16x8*)(ktc + row * 64 + (((g + 4) ^ (row & 7)) << 3));
            acc = __builtin_amdgcn_mfma_f32_16x16x32_bf16(kf0, qf0, acc, 0, 0, 0);
            acc = __builtin_amdgcn_mfma_f32_16x16x32_bf16(kf1, qf1, acc, 0, 0, 0);
#pragma unroll
            for (int r = 0; r < 4; ++r) {
                float m = rintf(acc[r] * rr);          // |dot*rr| < 127.0001 -> no clamp
                U += exp2f(kk * m);
            }
        }
    }
    U += __shfl_xor(U, 16, 64);
    U += __shfl_xor(U, 32, 64);
    float lu = log2f(U);

    // ---- sweep 2: scores -> packed pbits -> PV ----
    f32x4 oacc[4];
#pragma unroll
    for (int dt = 0; dt < 4; ++dt) oacc[dt] = (f32x4){0.f, 0.f, 0.f, 0.f};
    ushort* myps = (ushort*)ps[w];
    __syncthreads();                       // all waves done with sweep-1 buffers
    stage_k_tile(kbase, kt[0], tid);
    stage_vT_tile(vbase, vt[0], tid);
    for (int st = 0; st < NT; ++st) {
        __syncthreads();
        if (st + 1 < NT) {
            stage_k_tile(kbase + (size_t)(st + 1) * 64 * K3C, kt[(st + 1) & 1], tid);
            stage_vT_tile(vbase + (size_t)(st + 1) * 64 * K3C, vt[(st + 1) & 1], tid);
        }
        const ushort* ktc = kt[st & 1];
        const ushort* vtc = vt[st & 1];
#pragma unroll
        for (int jt = 0; jt < 4; ++jt) {
            int row = (jt << 4) + qr;
            f32x4 acc = {0.f, 0.f, 0.f, 0.f};
            s16x8 kf0 = *(s16x8*)(ktc + row * 64 + (((g    ) ^ (row & 7)) << 3));
            s16x8 kf1 = *(s16x8*)(ktc + row * 64 + (((g + 4) ^ (row & 7)) << 3));
            acc = __builtin_amdgcn_mfma_f32_16x16x32_bf16(kf0, qf0, acc, 0, 0, 0);
            acc = __builtin_amdgcn_mfma_f32_16x16x32_bf16(kf1, qf1, acc, 0, 0, 0);
            int lg[4];
#pragma unroll
            for (int r = 0; r < 4; ++r) {
                float m = rintf(acc[r] * rr);
                float tt = lu - kk * m;
                lg[r] = (int)fminf(fmaxf(rintf(tt), 0.0f), 15.0f);
            }
            unsigned w0 = (unsigned)(((127 - lg[0]) << 7) | ((127 - lg[1]) << 23));
            unsigned w1 = (unsigned)(((127 - lg[2]) << 7) | ((127 - lg[3]) << 23));
            int off = qr * 64 + (((jt << 4) + ((g >> 1) << 3)) ^ ((qr & 7) << 3)) + ((g & 1) << 2);
            *(u32x2*)(myps + off) = (u32x2){w0, w1};
        }
        // PV: O[16 x 64] += P[16 x 64] * V[64 x 64]
#pragma unroll
        for (int kc = 0; kc < 2; ++kc) {
            int poff = qr * 64 + (((kc << 5) + (g << 3)) ^ ((qr & 7) << 3));
            s16x8 pf = *(s16x8*)(myps + poff);
#pragma unroll
            for (int dt = 0; dt < 4; ++dt) {
                int drow = (dt << 4) + qr;
                s16x8 vf = *(s16x8*)(vtc + drow * 64 +
                                     (((((kc << 2) + g) ^ (drow & 7)) ^ ((drow >> 3) & 7)) << 3));
                oacc[dt] = __builtin_amdgcn_mfma_f32_16x16x32_bf16(pf, vf, oacc[dt], 0, 0, 0);
            }
        }
    }
    // write O (scale codes back by s_qkv)
#pragma unroll
    for (int dt = 0; dt < 4; ++dt)
#pragma unroll
        for (int r = 0; r < 4; ++r) {
            int orow = i0 + w * 16 + (g << 2) + r;
            O[(size_t)(b * NN + orow) * NC + h * ND + (dt << 4) + qr] = s * oacc[dt][r];
        }
}

// ---------------------------------------------------------------------------
// launch
// ---------------------------------------------------------------------------
extern "C" void kernel_launch(void* const* d_in, const int* in_sizes, int n_in,
                              void* d_out, int out_size, void* d_ws, size_t ws_size,
                              hipStream_t stream) {
    const float* x      = (const float*)d_in[0];
    const float* w_qkv  = (const float*)d_in[1];
    const float* b_qkv  = (const float*)d_in[2];
    const float* w_out  = (const float*)d_in[3];
    const float* b_out  = (const float*)d_in[4];
    float* out = (float*)d_out;

    // ---- workspace layout (proven 56.6 MB envelope, lifetime-overlapped) ----
    char* ws = (char*)d_ws;
    unsigned* u = (unsigned*)ws;                  // 0:wqkv 1:wout 2:qkv 3:maxdot 4:out
    const size_t qkvB = (size_t)ROWS * K3C * 4;            // 37.75 MB
    float*  qkv     = (float*)(ws + 256);                  // f32 qkv (gemm1..quantcodes)
    float*  out_tmp = (float*)(ws + 256);                  // gemm2 out (after qkv dead)
    ushort* woc     = (ushort*)(ws + 256 + 16 * 1024 * 1024);  // w_out codes (after qkv dead)
    char*   codesRg = ws + 256 + qkvB;                     // 18.87 MB region
    ushort* codes   = (ushort*)codesRg;                    // qkv codes (quantcodes..attn_fused)
    ushort* xsplit  = (ushort*)codesRg;                    // 3-term split of x / O
    ushort* wqc     = (ushort*)d_out;                      // w_qkv codes staged in d_out,
                                                           // dead before attn_fused writes O

    hipMemsetAsync(u, 0, 64, stream);

    // weight maxima + codes
    maxabs_kernel<<<512, 256, 0, stream>>>(w_qkv, (long long)K3C * NC, u + 0);
    maxabs_kernel<<<512, 256, 0, stream>>>(w_out, (long long)NC * NC, u + 1);
    quantcodes_kernel<<<512, 256, 0, stream>>>(w_qkv, wqc, (long long)K3C * NC, u + 0);

    // x -> 3-term split, then GEMM1 (fused maxabs of qkv -> u+2)
    split3_kernel<<<1024, 256, 0, stream>>>(x, xsplit, (long long)ROWS * NC);
    gemm3_mfma_kernel<<<dim3(K3C / 128, ROWS / 128), 256, 0, stream>>>(xsplit, wqc, b_qkv,
                                                                       qkv, K3C, u + 0, u + 2);
    // qact_qkv -> codes (clobbers xsplit, dead)
    quantcodes_kernel<<<2048, 256, 0, stream>>>(qkv, codes, (long long)ROWS * K3C, u + 2);
    // w_out codes into dead qkv-f32 region (after quantcodes above)
    quantcodes_kernel<<<256, 256, 0, stream>>>(w_out, woc, (long long)NC * NC, u + 1);

    // attention (O f32 -> d_out; clobbers wqc, dead)
    attn_maxdot_kernel<<<dim3(NN / 64, NHEADS), 256, 0, stream>>>(codes, u + 3);
    attn_fused_kernel<<<dim3(NN / 64, NHEADS), 256, 0, stream>>>(codes, u + 2, u + 3, out);

    // O -> 3-term split (clobbers codes, dead), then GEMM2 (fused maxabs -> u+4)
    split3_kernel<<<1024, 256, 0, stream>>>(out, xsplit, (long long)ROWS * NC);
    gemm3_mfma_kernel<<<dim3(NC / 128, ROWS / 128), 256, 0, stream>>>(xsplit, woc, b_out,
                                                                      out_tmp, NC, u + 1, u + 4);
    // qact_out -> d_out
    quant_kernel<<<1024, 256, 0, stream>>>(out_tmp, out, (long long)ROWS * NC, u + 4);
}